// Round 5
// baseline (320.126 us; speedup 1.0000x reference)
//
#include <hip/hip_runtime.h>

typedef __bf16 bf16;
typedef unsigned int u32;
typedef __bf16 bf16x8 __attribute__((ext_vector_type(8)));
typedef float f32x4 __attribute__((ext_vector_type(4)));
typedef float f32x16 __attribute__((ext_vector_type(16)));

#define DEV __device__ __forceinline__

// async global->LDS, 16B per lane; lds base must be wave-uniform (HW adds lane*16)
DEV void gload_lds16(const void* g, void* l) {
  __builtin_amdgcn_global_load_lds((const __attribute__((address_space(1))) void*)g,
                                   (__attribute__((address_space(3))) void*)l,
                                   16, 0, 0);
}

DEV u32 pack2(float a, float b) {
  unsigned short ua = __builtin_bit_cast(unsigned short, (bf16)a);
  unsigned short ub = __builtin_bit_cast(unsigned short, (bf16)b);
  return (u32)ua | ((u32)ub << 16);
}

// ---------------- cast fp32 -> bf16 for Q,K,V in one launch ----------------
__global__ void cast3_kernel(const float* __restrict__ a, const float* __restrict__ b,
                             const float* __restrict__ c, bf16* __restrict__ oa,
                             bf16* __restrict__ ob, bf16* __restrict__ oc, int n8) {
  const float* in = blockIdx.y == 0 ? a : blockIdx.y == 1 ? b : c;
  bf16* out = blockIdx.y == 0 ? oa : blockIdx.y == 1 ? ob : oc;
  int idx = blockIdx.x * blockDim.x + threadIdx.x;
  int stride = gridDim.x * blockDim.x;
  for (int i = idx; i < n8; i += stride) {
    const float4* p = (const float4*)(in + (size_t)i * 8);
    float4 x = p[0], y = p[1];
    bf16x8 v;
    v[0] = (bf16)x.x; v[1] = (bf16)x.y; v[2] = (bf16)x.z; v[3] = (bf16)x.w;
    v[4] = (bf16)y.x; v[5] = (bf16)y.y; v[6] = (bf16)y.z; v[7] = (bf16)y.w;
    *(bf16x8*)(out + (size_t)i * 8) = v;
  }
}

// ---------------- transpose + cast + scale: in[R][C] f32 -> out[C][R] bf16 ----------------
__global__ void transpose_cast(const float* __restrict__ in, bf16* __restrict__ out,
                               int R, int C, float scale) {
  __shared__ float tile[32][33];
  int c0 = blockIdx.x * 32, r0 = blockIdx.y * 32;
  int tx = threadIdx.x & 31, ty = threadIdx.x >> 5;  // 256 threads = 32x8
  for (int i = ty; i < 32; i += 8) tile[i][tx] = in[(size_t)(r0 + i) * C + c0 + tx];
  __syncthreads();
  for (int i = ty; i < 32; i += 8)
    out[(size_t)(c0 + i) * R + r0 + tx] = (bf16)(tile[tx][i] * scale);
}

// ---------------- bf16 GEMM, B given transposed (Bt[N][K]) ----------------
// m97 structure: BK=32, global_load_lds width 16, each wave owns a 64x64 subtile.
// OMODE 0: C[M][N] row-major.  OMODE 1: vT store — C[(b*64+col)*2048 + (row&2047)], b=row>>11.
template <int BM, int BN, typename OutT, int OMODE>
__global__ __launch_bounds__((BM / 64) * (BN / 64) * 64)
void gemm_bt(const bf16* __restrict__ A, const bf16* __restrict__ Bt,
             OutT* __restrict__ C, int M, int N, int K) {
  constexpr int WC = BN / 64;
  constexpr int NW = (BM / 64) * WC;
  constexpr int THREADS = NW * 64;
  __shared__ __align__(16) bf16 As[BM * 32];
  __shared__ __align__(16) bf16 Bs[BN * 32];
  const int tid = threadIdx.x;
  const int wid = tid >> 6, lane = tid & 63;
  const int wr = wid / WC, wc = wid % WC;
  const int lx = lane & 15, g = lane >> 4;
  const size_t bm = (size_t)blockIdx.x * BM;
  const size_t bn = (size_t)blockIdx.y * BN;
  f32x4 acc[4][4] = {};

  for (int k0 = 0; k0 < K; k0 += 32) {
#pragma unroll
    for (int i = 0; i < (BM * 4) / THREADS; ++i) {
      int c = i * THREADS + wid * 64 + lane;
      const bf16* gp = A + (bm + (size_t)(c >> 2)) * K + k0 + (c & 3) * 8;
      gload_lds16(gp, (char*)As + (size_t)(i * THREADS + wid * 64) * 16);
    }
#pragma unroll
    for (int i = 0; i < (BN * 4) / THREADS; ++i) {
      int c = i * THREADS + wid * 64 + lane;
      const bf16* gp = Bt + (bn + (size_t)(c >> 2)) * K + k0 + (c & 3) * 8;
      gload_lds16(gp, (char*)Bs + (size_t)(i * THREADS + wid * 64) * 16);
    }
    __syncthreads();
    bf16x8 af[4], bfr[4];
#pragma unroll
    for (int m = 0; m < 4; ++m)
      af[m] = *(const bf16x8*)&As[(wr * 64 + m * 16 + lx) * 32 + g * 8];
#pragma unroll
    for (int n = 0; n < 4; ++n)
      bfr[n] = *(const bf16x8*)&Bs[(wc * 64 + n * 16 + lx) * 32 + g * 8];
#pragma unroll
    for (int m = 0; m < 4; ++m)
#pragma unroll
      for (int n = 0; n < 4; ++n)
        acc[m][n] = __builtin_amdgcn_mfma_f32_16x16x32_bf16(af[m], bfr[n], acc[m][n], 0, 0, 0);
    __syncthreads();
  }

#pragma unroll
  for (int m = 0; m < 4; ++m) {
#pragma unroll
    for (int n = 0; n < 4; ++n) {
      size_t row = bm + wr * 64 + m * 16 + g * 4;
      size_t col = bn + wc * 64 + n * 16 + lx;
#pragma unroll
      for (int j = 0; j < 4; ++j) {
        float v = acc[m][n][j];
        if constexpr (OMODE == 0) {
          C[(row + j) * N + col] = (OutT)v;
        } else {
          size_t r = row + j;
          size_t bb = r >> 11, nn = r & 2047;
          C[(bb * 64 + col) * 2048 + nn] = (OutT)v;
        }
      }
    }
  }
}

// ---------------- causal multi-query flash attention (swapped QK^T, 32x32 MFMA) ----
// grid (64 strips, 16 heads, 4 batch), ONE wave per block, strip = 63 - bx so the
// longest strips dispatch first (load balance with ~all waves resident).
// S^T = mfma(K, Q): lane holds 16 scores of query (lane&31),
// key = kt0 + (r&3)+8*(r>>2)+4*(lane>>5). Softmax in-register; K register
// double-buffered (prefetch t+1 before softmax); P fragments rebuilt with
// shfl_xor(32) + select (verified in round 2); defer-max skips O-rescale.
__global__ __launch_bounds__(64, 3)
void attn_kernel(const bf16* __restrict__ q, const bf16* __restrict__ k,
                 const bf16* __restrict__ vT, bf16* __restrict__ o) {
  const int h = blockIdx.y, b = blockIdx.z;
  const int lane = threadIdx.x;
  const int lq = lane & 31, hi = lane >> 5;
  const int strip = 63 - blockIdx.x;
  const int qb = strip * 32;
  __shared__ float bc[32];

  const bf16* kb = k + (size_t)b * 2048 * 64;
  const bf16* vb = vT + (size_t)b * 64 * 2048;

  bf16x8 qf[4];
  const bf16* qrow = q + (size_t)(b * 2048 + qb + lq) * 1024 + h * 64 + hi * 8;
#pragma unroll
  for (int i = 0; i < 4; ++i) qf[i] = *(const bf16x8*)(qrow + i * 16);

  f32x16 O0 = {}, O1 = {};
  float m = -__builtin_inff(), l = 0.f;
  const int nt = strip + 1;

  // K tile 0 in registers
  const bf16* krow0 = kb + (size_t)lq * 64 + hi * 8;
  bf16x8 kf[4];
#pragma unroll
  for (int i = 0; i < 4; ++i) kf[i] = *(const bf16x8*)(krow0 + i * 16);

  const bf16* vrow = vb + (size_t)lq * 2048 + hi * 8;

  for (int t = 0; t < nt; ++t) {
    const int kt0 = t * 32;
    // V for tile t (consumed after softmax — latency naturally hidden)
    bf16x8 vf[2][2];
#pragma unroll
    for (int d = 0; d < 2; ++d)
#pragma unroll
      for (int ks = 0; ks < 2; ++ks)
        vf[d][ks] = *(const bf16x8*)(vrow + (size_t)d * 32 * 2048 + kt0 + ks * 16);

    // prefetch K tile t+1 (clamped; redundant load on last iter is harmless)
    const int tn = (t + 1 < nt) ? t + 1 : t;
    const bf16* krn = kb + ((size_t)(tn * 32) + lq) * 64 + hi * 8;
    bf16x8 kf2[4];
#pragma unroll
    for (int i = 0; i < 4; ++i) kf2[i] = *(const bf16x8*)(krn + i * 16);

    // S^T[key][q]: 4 MFMAs over dk=64
    f32x16 S = {};
#pragma unroll
    for (int i = 0; i < 4; ++i)
      S = __builtin_amdgcn_mfma_f32_32x32x16_bf16(kf[i], qf[i], S, 0, 0, 0);

    if (t == nt - 1) {  // diagonal tile: kt0 == qb, mask key_local > q_local
#pragma unroll
      for (int r = 0; r < 16; ++r) {
        int kr = (r & 3) + 8 * (r >> 2) + 4 * hi;
        if (kr > lq) S[r] = -__builtin_inff();
      }
    }

    // row max via max3-friendly triples
    float pm = fmaxf(fmaxf(S[0], S[1]), S[2]);
    pm = fmaxf(fmaxf(pm, S[3]), S[4]);
    pm = fmaxf(fmaxf(pm, S[5]), S[6]);
    pm = fmaxf(fmaxf(pm, S[7]), S[8]);
    pm = fmaxf(fmaxf(pm, S[9]), S[10]);
    pm = fmaxf(fmaxf(pm, S[11]), S[12]);
    pm = fmaxf(fmaxf(pm, S[13]), S[14]);
    pm = fmaxf(pm, S[15]);
    pm = fmaxf(pm, __shfl_xor(pm, 32));

    if (!__all(pm <= m + 8.0f)) {  // rescale path (rare after warmup)
      float mn = fmaxf(m, pm);
      float fac = __builtin_amdgcn_exp2f(m - mn);
      m = mn;
      l *= fac;
      if (hi == 0) bc[lq] = fac;
      __threadfence_block();
#pragma unroll
      for (int r = 0; r < 16; ++r) {
        float fr = bc[(r & 3) + 8 * (r >> 2) + 4 * hi];
        O0[r] *= fr;
        O1[r] *= fr;
      }
    }

    // exp + pack rolling pairs (cvt_pk fuses; S dies early)
    float ls = 0.f;
    u32 w[8];
#pragma unroll
    for (int i = 0; i < 8; ++i) {
      float e0 = __builtin_amdgcn_exp2f(S[2 * i] - m);
      float e1 = __builtin_amdgcn_exp2f(S[2 * i + 1] - m);
      ls += e0 + e1;
      w[i] = pack2(e0, e1);
    }
    ls += __shfl_xor(ls, 32);
    l += ls;

    // rebuild PV A-fragments: pack to bf16 pairs, exchange across lane-32 halves
    // (verified layout from round 2: shfl_xor + select)
    u32 sw0 = (u32)__shfl_xor((int)w[0], 32), sw1 = (u32)__shfl_xor((int)w[1], 32);
    u32 sw2 = (u32)__shfl_xor((int)w[2], 32), sw3 = (u32)__shfl_xor((int)w[3], 32);
    u32 sw4 = (u32)__shfl_xor((int)w[4], 32), sw5 = (u32)__shfl_xor((int)w[5], 32);
    u32 sw6 = (u32)__shfl_xor((int)w[6], 32), sw7 = (u32)__shfl_xor((int)w[7], 32);
    union { u32 d[4]; bf16x8 v; } f0, f1;
    f0.d[0] = hi ? sw2 : w[0];
    f0.d[1] = hi ? sw3 : w[1];
    f0.d[2] = hi ? w[2] : sw0;
    f0.d[3] = hi ? w[3] : sw1;
    f1.d[0] = hi ? sw6 : w[4];
    f1.d[1] = hi ? sw7 : w[5];
    f1.d[2] = hi ? w[6] : sw4;
    f1.d[3] = hi ? w[7] : sw5;

    O0 = __builtin_amdgcn_mfma_f32_32x32x16_bf16(f0.v, vf[0][0], O0, 0, 0, 0);
    O0 = __builtin_amdgcn_mfma_f32_32x32x16_bf16(f1.v, vf[0][1], O0, 0, 0, 0);
    O1 = __builtin_amdgcn_mfma_f32_32x32x16_bf16(f0.v, vf[1][0], O1, 0, 0, 0);
    O1 = __builtin_amdgcn_mfma_f32_32x32x16_bf16(f1.v, vf[1][1], O1, 0, 0, 0);

#pragma unroll
    for (int i = 0; i < 4; ++i) kf[i] = kf2[i];
  }

  // epilogue: normalize by 1/l (broadcast per output row) and store
  float linv = 1.0f / l;
  if (hi == 0) bc[lq] = linv;
  __threadfence_block();
#pragma unroll
  for (int r = 0; r < 16; ++r) {
    int row = (r & 3) + 8 * (r >> 2) + 4 * hi;
    float sc = bc[row];
    size_t base = (size_t)(b * 2048 + qb + row) * 1024 + h * 64;
    o[base + lq] = (bf16)(O0[r] * sc);
    o[base + 32 + lq] = (bf16)(O1[r] * sc);
  }
}

// ---------------- launch ----------------
extern "C" void kernel_launch(void* const* d_in, const int* in_sizes, int n_in,
                              void* d_out, int out_size, void* d_ws, size_t ws_size,
                              hipStream_t stream) {
  const float* Q  = (const float*)d_in[0];
  const float* K  = (const float*)d_in[1];
  const float* V  = (const float*)d_in[2];
  const float* wq = (const float*)d_in[3];
  const float* wk = (const float*)d_in[4];
  const float* wv = (const float*)d_in[5];
  const float* wo = (const float*)d_in[6];
  float* out = (float*)d_out;

  char* ws = (char*)d_ws;
  bf16* Qb  = (bf16*)(ws);                          // 8192x1024  (16 MB)
  bf16* Kb  = (bf16*)(ws + (16ull << 20));          // 16 MB
  bf16* Vb  = (bf16*)(ws + (32ull << 20));          // 16 MB
  bf16* qp  = (bf16*)(ws + (48ull << 20));          // q proj bf16, 16 MB
  bf16* ab  = (bf16*)(ws + (64ull << 20));          // attn out bf16, 16 MB
  bf16* kp  = (bf16*)(ws + (80ull << 20));          // 8192x64, 1 MB
  bf16* vTp = (bf16*)(ws + (81ull << 20));          // [4][64][2048], 1 MB
  bf16* wqT = (bf16*)(ws + (82ull << 20));          // 2 MB
  bf16* woT = (bf16*)(ws + (84ull << 20));          // 2 MB
  bf16* wkT = (bf16*)(ws + (86ull << 20));          // 128 KB
  bf16* wvT = (bf16*)(ws + (86ull << 20) + (1ull << 18));

  const int N8 = 8192 * 1024 / 8;
  cast3_kernel<<<dim3(1024, 3), 256, 0, stream>>>(Q, K, V, Qb, Kb, Vb, N8);

  // fold softmax scale (1/sqrt(64)) and log2(e) into Wq (exp2-based softmax)
  const float SCALE = 0.125f * 1.44269504088896340736f;
  transpose_cast<<<dim3(32, 32), 256, 0, stream>>>(wq, wqT, 1024, 1024, SCALE);
  transpose_cast<<<dim3(2, 32), 256, 0, stream>>>(wk, wkT, 1024, 64, 1.0f);
  transpose_cast<<<dim3(2, 32), 256, 0, stream>>>(wv, wvT, 1024, 64, 1.0f);
  transpose_cast<<<dim3(32, 32), 256, 0, stream>>>(wo, woT, 1024, 1024, 1.0f);

  gemm_bt<128, 128, bf16, 0><<<dim3(64, 8), 256, 0, stream>>>(Qb, wqT, qp, 8192, 1024, 1024);
  gemm_bt<128, 64, bf16, 0><<<dim3(64, 1), 128, 0, stream>>>(Kb, wkT, kp, 8192, 64, 1024);
  gemm_bt<128, 64, bf16, 1><<<dim3(64, 1), 128, 0, stream>>>(Vb, wvT, vTp, 8192, 64, 1024);

  attn_kernel<<<dim3(64, 16, 4), 64, 0, stream>>>(qp, kp, vTp, ab);

  gemm_bt<128, 128, float, 0><<<dim3(64, 8), 256, 0, stream>>>(ab, woT, out, 8192, 1024, 1024);
}

// Round 6
// 210.325 us; speedup vs baseline: 1.5221x; 1.5221x over previous
//
#include <hip/hip_runtime.h>

typedef __bf16 bf16;
typedef unsigned int u32;
typedef __bf16 bf16x8 __attribute__((ext_vector_type(8)));
typedef float f32x4 __attribute__((ext_vector_type(4)));
typedef float f32x16 __attribute__((ext_vector_type(16)));

#define DEV __device__ __forceinline__

// async global->LDS, 16B per lane; lds base must be wave-uniform (HW adds lane*16);
// global source address IS per-lane (m173)
DEV void gload_lds16(const void* g, void* l) {
  __builtin_amdgcn_global_load_lds((const __attribute__((address_space(1))) void*)g,
                                   (__attribute__((address_space(3))) void*)l,
                                   16, 0, 0);
}

DEV u32 pack2(float a, float b) {
  unsigned short ua = __builtin_bit_cast(unsigned short, (bf16)a);
  unsigned short ub = __builtin_bit_cast(unsigned short, (bf16)b);
  return (u32)ua | ((u32)ub << 16);
}

// ---------------- cast fp32 -> bf16 for Q,K,V in one launch ----------------
__global__ void cast3_kernel(const float* __restrict__ a, const float* __restrict__ b,
                             const float* __restrict__ c, bf16* __restrict__ oa,
                             bf16* __restrict__ ob, bf16* __restrict__ oc, int n8) {
  const float* in = blockIdx.y == 0 ? a : blockIdx.y == 1 ? b : c;
  bf16* out = blockIdx.y == 0 ? oa : blockIdx.y == 1 ? ob : oc;
  int idx = blockIdx.x * blockDim.x + threadIdx.x;
  int stride = gridDim.x * blockDim.x;
  for (int i = idx; i < n8; i += stride) {
    const float4* p = (const float4*)(in + (size_t)i * 8);
    float4 x = p[0], y = p[1];
    bf16x8 v;
    v[0] = (bf16)x.x; v[1] = (bf16)x.y; v[2] = (bf16)x.z; v[3] = (bf16)x.w;
    v[4] = (bf16)y.x; v[5] = (bf16)y.y; v[6] = (bf16)y.z; v[7] = (bf16)y.w;
    *(bf16x8*)(out + (size_t)i * 8) = v;
  }
}

// ---------------- transpose + cast + scale: in[R][C] f32 -> out[C][R] bf16 ----------------
__global__ void transpose_cast(const float* __restrict__ in, bf16* __restrict__ out,
                               int R, int C, float scale) {
  __shared__ float tile[32][33];
  int c0 = blockIdx.x * 32, r0 = blockIdx.y * 32;
  int tx = threadIdx.x & 31, ty = threadIdx.x >> 5;  // 256 threads = 32x8
  for (int i = ty; i < 32; i += 8) tile[i][tx] = in[(size_t)(r0 + i) * C + c0 + tx];
  __syncthreads();
  for (int i = ty; i < 32; i += 8)
    out[(size_t)(c0 + i) * R + r0 + tx] = (bf16)(tile[tx][i] * scale);
}

// ---------------- bf16 GEMM, B given transposed (Bt[N][K]) ----------------
// m97 structure: BK=32, global_load_lds width 16, each wave owns a 64x64 subtile.
// OMODE 0: C[M][N] row-major.
// OMODE 1: V-tile store — C[b*131072 + (key&2047)/32*2048 + d*32 + (key&31)], 4KB tiles.
template <int BM, int BN, typename OutT, int OMODE>
__global__ __launch_bounds__((BM / 64) * (BN / 64) * 64)
void gemm_bt(const bf16* __restrict__ A, const bf16* __restrict__ Bt,
             OutT* __restrict__ C, int M, int N, int K) {
  constexpr int WC = BN / 64;
  constexpr int NW = (BM / 64) * WC;
  constexpr int THREADS = NW * 64;
  __shared__ __align__(16) bf16 As[BM * 32];
  __shared__ __align__(16) bf16 Bs[BN * 32];
  const int tid = threadIdx.x;
  const int wid = tid >> 6, lane = tid & 63;
  const int wr = wid / WC, wc = wid % WC;
  const int lx = lane & 15, g = lane >> 4;
  const size_t bm = (size_t)blockIdx.x * BM;
  const size_t bn = (size_t)blockIdx.y * BN;
  f32x4 acc[4][4] = {};

  for (int k0 = 0; k0 < K; k0 += 32) {
#pragma unroll
    for (int i = 0; i < (BM * 4) / THREADS; ++i) {
      int c = i * THREADS + wid * 64 + lane;
      const bf16* gp = A + (bm + (size_t)(c >> 2)) * K + k0 + (c & 3) * 8;
      gload_lds16(gp, (char*)As + (size_t)(i * THREADS + wid * 64) * 16);
    }
#pragma unroll
    for (int i = 0; i < (BN * 4) / THREADS; ++i) {
      int c = i * THREADS + wid * 64 + lane;
      const bf16* gp = Bt + (bn + (size_t)(c >> 2)) * K + k0 + (c & 3) * 8;
      gload_lds16(gp, (char*)Bs + (size_t)(i * THREADS + wid * 64) * 16);
    }
    __syncthreads();
    bf16x8 af[4], bfr[4];
#pragma unroll
    for (int m = 0; m < 4; ++m)
      af[m] = *(const bf16x8*)&As[(wr * 64 + m * 16 + lx) * 32 + g * 8];
#pragma unroll
    for (int n = 0; n < 4; ++n)
      bfr[n] = *(const bf16x8*)&Bs[(wc * 64 + n * 16 + lx) * 32 + g * 8];
#pragma unroll
    for (int m = 0; m < 4; ++m)
#pragma unroll
      for (int n = 0; n < 4; ++n)
        acc[m][n] = __builtin_amdgcn_mfma_f32_16x16x32_bf16(af[m], bfr[n], acc[m][n], 0, 0, 0);
    __syncthreads();
  }

#pragma unroll
  for (int m = 0; m < 4; ++m) {
#pragma unroll
    for (int n = 0; n < 4; ++n) {
      size_t row = bm + wr * 64 + m * 16 + g * 4;
      size_t col = bn + wc * 64 + n * 16 + lx;
#pragma unroll
      for (int j = 0; j < 4; ++j) {
        float v = acc[m][n][j];
        if constexpr (OMODE == 0) {
          C[(row + j) * N + col] = (OutT)v;
        } else {
          size_t r = row + j;
          size_t bb = r >> 11, nn = r & 2047;
          C[bb * 131072 + (nn >> 5) * 2048 + col * 32 + (nn & 31)] = (OutT)v;
        }
      }
    }
  }
}

// ---------------- causal multi-query flash attention (swapped QK^T, 32x32 MFMA) ----
// grid (32 strip-pairs, 4 head-groups, 4 batch), 256 threads = 4 waves = 4 HEADS
// sharing one (strip,batch): MQA K/V staged ONCE per block into LDS (double-buffered,
// XOR-swizzled for conflict-free b128 reads; swizzle applied at staging SOURCE and at
// ds_read — rule 21). Strip pairing (63-p then p) -> uniform 65 tiles/block; 512 blocks
// = 2/CU, all resident. Softmax in-register (verified round-2 path).
__global__ __launch_bounds__(256, 4)
void attn_kernel(const bf16* __restrict__ q, const bf16* __restrict__ k,
                 const bf16* __restrict__ vt, bf16* __restrict__ o) {
  const int hg = blockIdx.y, b = blockIdx.z;
  const int wid = threadIdx.x >> 6, lane = threadIdx.x & 63;
  const int lq = lane & 31, hi = lane >> 5;
  const int h = hg * 4 + wid;
  const int pairIdx = blockIdx.x;  // 0..31

  __shared__ __align__(16) char Ks[2][4096];  // K tile: 32 keys x 64d, swizzled
  __shared__ __align__(16) char Vs[2][4096];  // V tile: 64d x 32 keys, swizzled
  __shared__ float bc[4][32];

  const bf16* kb = k + (size_t)b * 2048 * 64;            // [key][64]
  const char* vbase = (const char*)vt + (size_t)b * 262144;  // [tile][d][key32]

  // stage K tile kt (4KB contiguous): LDS granule g <- tile granule g^((g>>3)&7)
  auto stageK = [&](int bi, int kt) {
    int src = (wid * 64 + lane) ^ ((lane >> 3) & 7);
    gload_lds16((const char*)(kb + (size_t)kt * 2048) + src * 16, &Ks[bi][wid * 1024]);
  };
  // stage V tile kt: LDS granule g <- tile granule (g&~3)|((g&3)^((g>>3)&3))
  auto stageV = [&](int bi, int kt) {
    int g = wid * 64 + lane;
    int src = (g & ~3) | ((g & 3) ^ ((lane >> 3) & 3));
    gload_lds16(vbase + (size_t)kt * 4096 + src * 16, &Vs[bi][wid * 1024]);
  };

#pragma unroll 1
  for (int rep = 0; rep < 2; ++rep) {
    const int strip = rep ? pairIdx : 63 - pairIdx;
    const int qb = strip * 32;
    const int nt = strip + 1;

    bf16x8 qf[4];
    const bf16* qrow = q + (size_t)(b * 2048 + qb + lq) * 1024 + h * 64 + hi * 8;
#pragma unroll
    for (int i = 0; i < 4; ++i) qf[i] = *(const bf16x8*)(qrow + i * 16);

    f32x16 O0 = {}, O1 = {};
    float m = -__builtin_inff(), l = 0.f;

    stageK(0, 0);
    stageV(0, 0);
    __syncthreads();
    int cur = 0;

    for (int t = 0; t < nt; ++t) {
      if (t + 1 < nt) {
        stageK(cur ^ 1, t + 1);
        stageV(cur ^ 1, t + 1);
      }

      // K frag i: logical granule lq*8+i*2+hi, swizzled ^(lq&7)
      bf16x8 kf[4];
#pragma unroll
      for (int i = 0; i < 4; ++i)
        kf[i] = *(const bf16x8*)&Ks[cur][((lq * 8 + i * 2 + hi) ^ (lq & 7)) * 16];
      // V frag (d,ks): logical granule (d*32+lq)*4 + ks*2+hi, col bits ^((lq>>1)&3)
      bf16x8 vf[2][2];
#pragma unroll
      for (int d = 0; d < 2; ++d)
#pragma unroll
        for (int ks = 0; ks < 2; ++ks)
          vf[d][ks] = *(const bf16x8*)
              &Vs[cur][((d * 32 + lq) * 4 + ((ks * 2 + hi) ^ ((lq >> 1) & 3))) * 16];

      // S^T[key][q]: 4 MFMAs over dk=64
      f32x16 S = {};
#pragma unroll
      for (int i = 0; i < 4; ++i)
        S = __builtin_amdgcn_mfma_f32_32x32x16_bf16(kf[i], qf[i], S, 0, 0, 0);

      if (t == nt - 1) {  // diagonal tile: mask key_local > q_local
#pragma unroll
        for (int r = 0; r < 16; ++r) {
          int kr = (r & 3) + 8 * (r >> 2) + 4 * hi;
          if (kr > lq) S[r] = -__builtin_inff();
        }
      }

      // row max
      float pm = fmaxf(fmaxf(S[0], S[1]), S[2]);
      pm = fmaxf(fmaxf(pm, S[3]), S[4]);
      pm = fmaxf(fmaxf(pm, S[5]), S[6]);
      pm = fmaxf(fmaxf(pm, S[7]), S[8]);
      pm = fmaxf(fmaxf(pm, S[9]), S[10]);
      pm = fmaxf(fmaxf(pm, S[11]), S[12]);
      pm = fmaxf(fmaxf(pm, S[13]), S[14]);
      pm = fmaxf(pm, S[15]);
      pm = fmaxf(pm, __shfl_xor(pm, 32));

      if (!__all(pm <= m + 8.0f)) {  // rescale path (rare after warmup)
        float mn = fmaxf(m, pm);
        float fac = __builtin_amdgcn_exp2f(m - mn);
        m = mn;
        l *= fac;
        if (hi == 0) bc[wid][lq] = fac;
        __threadfence_block();
#pragma unroll
        for (int r = 0; r < 16; ++r) {
          float fr = bc[wid][(r & 3) + 8 * (r >> 2) + 4 * hi];
          O0[r] *= fr;
          O1[r] *= fr;
        }
      }

      // exp + pack rolling pairs
      float ls = 0.f;
      u32 w[8];
#pragma unroll
      for (int i = 0; i < 8; ++i) {
        float e0 = __builtin_amdgcn_exp2f(S[2 * i] - m);
        float e1 = __builtin_amdgcn_exp2f(S[2 * i + 1] - m);
        ls += e0 + e1;
        w[i] = pack2(e0, e1);
      }
      ls += __shfl_xor(ls, 32);
      l += ls;

      // rebuild PV A-fragments (verified round-2 path): shfl_xor(32) + select
      u32 sw0 = (u32)__shfl_xor((int)w[0], 32), sw1 = (u32)__shfl_xor((int)w[1], 32);
      u32 sw2 = (u32)__shfl_xor((int)w[2], 32), sw3 = (u32)__shfl_xor((int)w[3], 32);
      u32 sw4 = (u32)__shfl_xor((int)w[4], 32), sw5 = (u32)__shfl_xor((int)w[5], 32);
      u32 sw6 = (u32)__shfl_xor((int)w[6], 32), sw7 = (u32)__shfl_xor((int)w[7], 32);
      union { u32 d[4]; bf16x8 v; } f0, f1;
      f0.d[0] = hi ? sw2 : w[0];
      f0.d[1] = hi ? sw3 : w[1];
      f0.d[2] = hi ? w[2] : sw0;
      f0.d[3] = hi ? w[3] : sw1;
      f1.d[0] = hi ? sw6 : w[4];
      f1.d[1] = hi ? sw7 : w[5];
      f1.d[2] = hi ? w[6] : sw4;
      f1.d[3] = hi ? w[7] : sw5;

      O0 = __builtin_amdgcn_mfma_f32_32x32x16_bf16(f0.v, vf[0][0], O0, 0, 0, 0);
      O0 = __builtin_amdgcn_mfma_f32_32x32x16_bf16(f1.v, vf[0][1], O0, 0, 0, 0);
      O1 = __builtin_amdgcn_mfma_f32_32x32x16_bf16(f0.v, vf[1][0], O1, 0, 0, 0);
      O1 = __builtin_amdgcn_mfma_f32_32x32x16_bf16(f1.v, vf[1][1], O1, 0, 0, 0);

      __syncthreads();  // own staging loads drained (vmcnt 0) + all waves done reading
      cur ^= 1;
    }

    // epilogue: normalize by 1/l (broadcast per output row) and store
    float linv = 1.0f / l;
    if (hi == 0) bc[wid][lq] = linv;
    __threadfence_block();
#pragma unroll
    for (int r = 0; r < 16; ++r) {
      int row = (r & 3) + 8 * (r >> 2) + 4 * hi;
      float sc = bc[wid][row];
      size_t base = (size_t)(b * 2048 + qb + row) * 1024 + h * 64;
      o[base + lq] = (bf16)(O0[r] * sc);
      o[base + 32 + lq] = (bf16)(O1[r] * sc);
    }
  }
}

// ---------------- launch ----------------
extern "C" void kernel_launch(void* const* d_in, const int* in_sizes, int n_in,
                              void* d_out, int out_size, void* d_ws, size_t ws_size,
                              hipStream_t stream) {
  const float* Q  = (const float*)d_in[0];
  const float* K  = (const float*)d_in[1];
  const float* V  = (const float*)d_in[2];
  const float* wq = (const float*)d_in[3];
  const float* wk = (const float*)d_in[4];
  const float* wv = (const float*)d_in[5];
  const float* wo = (const float*)d_in[6];
  float* out = (float*)d_out;

  char* ws = (char*)d_ws;
  bf16* Qb  = (bf16*)(ws);                          // 8192x1024  (16 MB)
  bf16* Kb  = (bf16*)(ws + (16ull << 20));          // 16 MB
  bf16* Vb  = (bf16*)(ws + (32ull << 20));          // 16 MB
  bf16* qp  = (bf16*)(ws + (48ull << 20));          // q proj bf16, 16 MB
  bf16* ab  = (bf16*)(ws + (64ull << 20));          // attn out bf16, 16 MB
  bf16* kp  = (bf16*)(ws + (80ull << 20));          // [b][key][64], 1 MB
  bf16* vTp = (bf16*)(ws + (81ull << 20));          // [b][tile][d][key32], 1 MB
  bf16* wqT = (bf16*)(ws + (82ull << 20));          // 2 MB
  bf16* woT = (bf16*)(ws + (84ull << 20));          // 2 MB
  bf16* wkT = (bf16*)(ws + (86ull << 20));          // 128 KB
  bf16* wvT = (bf16*)(ws + (86ull << 20) + (1ull << 18));

  const int N8 = 8192 * 1024 / 8;
  cast3_kernel<<<dim3(1024, 3), 256, 0, stream>>>(Q, K, V, Qb, Kb, Vb, N8);

  // fold softmax scale (1/sqrt(64)) and log2(e) into Wq (exp2-based softmax)
  const float SCALE = 0.125f * 1.44269504088896340736f;
  transpose_cast<<<dim3(32, 32), 256, 0, stream>>>(wq, wqT, 1024, 1024, SCALE);
  transpose_cast<<<dim3(2, 32), 256, 0, stream>>>(wk, wkT, 1024, 64, 1.0f);
  transpose_cast<<<dim3(2, 32), 256, 0, stream>>>(wv, wvT, 1024, 64, 1.0f);
  transpose_cast<<<dim3(32, 32), 256, 0, stream>>>(wo, woT, 1024, 1024, 1.0f);

  gemm_bt<128, 128, bf16, 0><<<dim3(64, 8), 256, 0, stream>>>(Qb, wqT, qp, 8192, 1024, 1024);
  gemm_bt<128, 64, bf16, 0><<<dim3(64, 1), 128, 0, stream>>>(Kb, wkT, kp, 8192, 64, 1024);
  gemm_bt<128, 64, bf16, 1><<<dim3(64, 1), 128, 0, stream>>>(Vb, wvT, vTp, 8192, 64, 1024);

  attn_kernel<<<dim3(32, 4, 4), 256, 0, stream>>>(qp, kp, vTp, ab);

  gemm_bt<128, 128, float, 0><<<dim3(64, 8), 256, 0, stream>>>(ab, woT, out, 8192, 1024, 1024);
}

// Round 7
// 195.218 us; speedup vs baseline: 1.6398x; 1.0774x over previous
//
#include <hip/hip_runtime.h>

typedef __bf16 bf16;
typedef unsigned int u32;
typedef __bf16 bf16x8 __attribute__((ext_vector_type(8)));
typedef float f32x4 __attribute__((ext_vector_type(4)));
typedef float f32x16 __attribute__((ext_vector_type(16)));

#define DEV __device__ __forceinline__

// async global->LDS, 16B per lane; lds base must be wave-uniform (HW adds lane*16);
// global source address IS per-lane (m173)
DEV void gload_lds16(const void* g, void* l) {
  __builtin_amdgcn_global_load_lds((const __attribute__((address_space(1))) void*)g,
                                   (__attribute__((address_space(3))) void*)l,
                                   16, 0, 0);
}

DEV u32 pack2(float a, float b) {
  unsigned short ua = __builtin_bit_cast(unsigned short, (bf16)a);
  unsigned short ub = __builtin_bit_cast(unsigned short, (bf16)b);
  return (u32)ua | ((u32)ub << 16);
}

// ---------------- cast fp32 -> bf16 for Q,K,V in one launch ----------------
__global__ void cast3_kernel(const float* __restrict__ a, const float* __restrict__ b,
                             const float* __restrict__ c, bf16* __restrict__ oa,
                             bf16* __restrict__ ob, bf16* __restrict__ oc, int n8) {
  const float* in = blockIdx.y == 0 ? a : blockIdx.y == 1 ? b : c;
  bf16* out = blockIdx.y == 0 ? oa : blockIdx.y == 1 ? ob : oc;
  int idx = blockIdx.x * blockDim.x + threadIdx.x;
  int stride = gridDim.x * blockDim.x;
  for (int i = idx; i < n8; i += stride) {
    const float4* p = (const float4*)(in + (size_t)i * 8);
    float4 x = p[0], y = p[1];
    bf16x8 v;
    v[0] = (bf16)x.x; v[1] = (bf16)x.y; v[2] = (bf16)x.z; v[3] = (bf16)x.w;
    v[4] = (bf16)y.x; v[5] = (bf16)y.y; v[6] = (bf16)y.z; v[7] = (bf16)y.w;
    *(bf16x8*)(out + (size_t)i * 8) = v;
  }
}

// ---------------- all weight transposes in ONE launch ----------------
// x<32: wq->wqT (scaled); x in [32,34): wk->wkvT rows 0-63; [34,36): wv->wkvT rows
// 64-127; [36,68): wo->woT. All R=1024 outputs.
__global__ void transpose_all(const float* __restrict__ wq, const float* __restrict__ wk,
                              const float* __restrict__ wv, const float* __restrict__ wo,
                              bf16* __restrict__ wqT, bf16* __restrict__ wkvT,
                              bf16* __restrict__ woT, float scale_q) {
  __shared__ float tile[32][33];
  int x = blockIdx.x;
  const float* in;
  bf16* out;
  int C;
  float scale = 1.0f;
  int c0;
  if (x < 32)      { in = wq; out = wqT;             C = 1024; c0 = x * 32; scale = scale_q; }
  else if (x < 34) { in = wk; out = wkvT;            C = 64;   c0 = (x - 32) * 32; }
  else if (x < 36) { in = wv; out = wkvT + 64 * 1024; C = 64;  c0 = (x - 34) * 32; }
  else             { in = wo; out = woT;             C = 1024; c0 = (x - 36) * 32; }
  int r0 = blockIdx.y * 32;
  int tx = threadIdx.x & 31, ty = threadIdx.x >> 5;  // 256 threads = 32x8
  for (int i = ty; i < 32; i += 8) tile[i][tx] = in[(size_t)(r0 + i) * C + c0 + tx];
  __syncthreads();
  for (int i = ty; i < 32; i += 8)
    out[(size_t)(c0 + i) * 1024 + r0 + tx] = (bf16)(tile[tx][i] * scale);
}

// ---------------- bf16 GEMM, B transposed (Bt[N][K]), m97 structure ----------------
// 128x128 tile, BK=32, global_load_lds w16, 4 waves each owning a 64x64 subtile.
template <typename OutT>
__global__ __launch_bounds__(256)
void gemm_bt(const bf16* __restrict__ A, const bf16* __restrict__ Bt,
             OutT* __restrict__ C, int M, int N, int K) {
  __shared__ __align__(16) bf16 As[128 * 32];
  __shared__ __align__(16) bf16 Bs[128 * 32];
  const int tid = threadIdx.x;
  const int wid = tid >> 6, lane = tid & 63;
  const int wr = wid >> 1, wc = wid & 1;
  const int lx = lane & 15, g = lane >> 4;
  const size_t bm = (size_t)blockIdx.x * 128;
  const size_t bn = (size_t)blockIdx.y * 128;
  f32x4 acc[4][4] = {};

  for (int k0 = 0; k0 < K; k0 += 32) {
#pragma unroll
    for (int i = 0; i < 2; ++i) {
      int c = i * 256 + wid * 64 + lane;
      const bf16* gp = A + (bm + (size_t)(c >> 2)) * K + k0 + (c & 3) * 8;
      gload_lds16(gp, (char*)As + (size_t)(i * 256 + wid * 64) * 16);
    }
#pragma unroll
    for (int i = 0; i < 2; ++i) {
      int c = i * 256 + wid * 64 + lane;
      const bf16* gp = Bt + (bn + (size_t)(c >> 2)) * K + k0 + (c & 3) * 8;
      gload_lds16(gp, (char*)Bs + (size_t)(i * 256 + wid * 64) * 16);
    }
    __syncthreads();
    bf16x8 af[4], bfr[4];
#pragma unroll
    for (int m = 0; m < 4; ++m)
      af[m] = *(const bf16x8*)&As[(wr * 64 + m * 16 + lx) * 32 + g * 8];
#pragma unroll
    for (int n = 0; n < 4; ++n)
      bfr[n] = *(const bf16x8*)&Bs[(wc * 64 + n * 16 + lx) * 32 + g * 8];
#pragma unroll
    for (int m = 0; m < 4; ++m)
#pragma unroll
      for (int n = 0; n < 4; ++n)
        acc[m][n] = __builtin_amdgcn_mfma_f32_16x16x32_bf16(af[m], bfr[n], acc[m][n], 0, 0, 0);
    __syncthreads();
  }

#pragma unroll
  for (int m = 0; m < 4; ++m)
#pragma unroll
    for (int n = 0; n < 4; ++n) {
      size_t row = bm + wr * 64 + m * 16 + g * 4;
      size_t col = bn + wc * 64 + n * 16 + lx;
#pragma unroll
      for (int j = 0; j < 4; ++j)
        C[(row + j) * N + col] = (OutT)acc[m][n][j];
    }
}

// ---------------- fused projections: q = Qb@wqT ; [k|v] = [Kb;Vb]@[wk|wv] ----------
// 1D grid 640 blocks. bid<512: q-proj tile (bm=(bid&63)*128, bn=(bid>>6)*128) -> qp.
// bid>=512: stacked-KV tile (bm=(bid-512)*128 of the 16384-row [Kb;Vb], bn=0,
// BN=128 = [k cols 0-63 | v cols 64-127]); epilogue routes k rows<8192 -> kp,
// v rows>=8192 -> vTp tile layout [b][key32-tile][d][key%32]; garbage quadrants dropped.
__global__ __launch_bounds__(256)
void proj_kernel(const bf16* __restrict__ Qb, const bf16* __restrict__ KVb,
                 const bf16* __restrict__ wqT, const bf16* __restrict__ wkvT,
                 bf16* __restrict__ qp, bf16* __restrict__ kp, bf16* __restrict__ vTp) {
  const int bid = blockIdx.x;
  const bool isq = bid < 512;
  const bf16* A = isq ? Qb : KVb;
  const bf16* Bt = isq ? wqT : wkvT;
  const size_t bm = isq ? (size_t)(bid & 63) * 128 : (size_t)(bid - 512) * 128;
  const size_t bn = isq ? (size_t)(bid >> 6) * 128 : 0;

  __shared__ __align__(16) bf16 As[128 * 32];
  __shared__ __align__(16) bf16 Bs[128 * 32];
  const int tid = threadIdx.x;
  const int wid = tid >> 6, lane = tid & 63;
  const int wr = wid >> 1, wc = wid & 1;
  const int lx = lane & 15, g = lane >> 4;
  f32x4 acc[4][4] = {};

  for (int k0 = 0; k0 < 1024; k0 += 32) {
#pragma unroll
    for (int i = 0; i < 2; ++i) {
      int c = i * 256 + wid * 64 + lane;
      const bf16* gp = A + (bm + (size_t)(c >> 2)) * 1024 + k0 + (c & 3) * 8;
      gload_lds16(gp, (char*)As + (size_t)(i * 256 + wid * 64) * 16);
    }
#pragma unroll
    for (int i = 0; i < 2; ++i) {
      int c = i * 256 + wid * 64 + lane;
      const bf16* gp = Bt + (bn + (size_t)(c >> 2)) * 1024 + k0 + (c & 3) * 8;
      gload_lds16(gp, (char*)Bs + (size_t)(i * 256 + wid * 64) * 16);
    }
    __syncthreads();
    bf16x8 af[4], bfr[4];
#pragma unroll
    for (int m = 0; m < 4; ++m)
      af[m] = *(const bf16x8*)&As[(wr * 64 + m * 16 + lx) * 32 + g * 8];
#pragma unroll
    for (int n = 0; n < 4; ++n)
      bfr[n] = *(const bf16x8*)&Bs[(wc * 64 + n * 16 + lx) * 32 + g * 8];
#pragma unroll
    for (int m = 0; m < 4; ++m)
#pragma unroll
      for (int n = 0; n < 4; ++n)
        acc[m][n] = __builtin_amdgcn_mfma_f32_16x16x32_bf16(af[m], bfr[n], acc[m][n], 0, 0, 0);
    __syncthreads();
  }

#pragma unroll
  for (int m = 0; m < 4; ++m)
#pragma unroll
    for (int n = 0; n < 4; ++n) {
      size_t row = bm + wr * 64 + m * 16 + g * 4;
      size_t col = bn + wc * 64 + n * 16 + lx;
#pragma unroll
      for (int j = 0; j < 4; ++j) {
        float v = acc[m][n][j];
        size_t r = row + j;
        if (isq) {
          qp[r * 1024 + col] = (bf16)v;
        } else if (col < 64) {
          if (r < 8192) kp[r * 64 + col] = (bf16)v;  // [b*2048+key][64]
        } else {
          if (r >= 8192) {
            size_t rr = r - 8192;
            size_t bb = rr >> 11, nn = rr & 2047;
            vTp[bb * 131072 + (nn >> 5) * 2048 + (col - 64) * 32 + (nn & 31)] = (bf16)v;
          }
        }
      }
    }
}

// ---------------- causal multi-query flash attention (swapped QK^T, 32x32 MFMA) ----
// grid (64 strips, 4 head-groups, 4 batch) = 1024 blocks, 256 threads = 4 waves =
// 4 HEADS sharing one (strip,batch): MQA K/V staged ONCE per block into LDS
// (double-buffered, XOR-swizzled: swizzle at staging SOURCE + at ds_read, rule 21).
// strip = 63-bx -> longest first. 4096 waves = 16/CU. Softmax in-register
// (verified round-2 path).
__global__ __launch_bounds__(256, 4)
void attn_kernel(const bf16* __restrict__ q, const bf16* __restrict__ k,
                 const bf16* __restrict__ vt, bf16* __restrict__ o) {
  const int hg = blockIdx.y, b = blockIdx.z;
  const int wid = threadIdx.x >> 6, lane = threadIdx.x & 63;
  const int lq = lane & 31, hi = lane >> 5;
  const int h = hg * 4 + wid;
  const int strip = 63 - blockIdx.x;
  const int qb = strip * 32;
  const int nt = strip + 1;

  __shared__ __align__(16) char Ks[2][4096];  // K tile: 32 keys x 64d, swizzled
  __shared__ __align__(16) char Vs[2][4096];  // V tile: 64d x 32 keys, swizzled
  __shared__ float bc[4][32];

  const bf16* kb = k + (size_t)b * 2048 * 64;                // [key][64]
  const char* vbase = (const char*)vt + (size_t)b * 262144;  // [tile][d][key32]

  // stage K tile kt (4KB contiguous): LDS granule g <- tile granule g^((g>>3)&7)
  auto stageK = [&](int bi, int kt) {
    int src = (wid * 64 + lane) ^ ((lane >> 3) & 7);
    gload_lds16((const char*)(kb + (size_t)kt * 2048) + src * 16, &Ks[bi][wid * 1024]);
  };
  // stage V tile kt: LDS granule g <- tile granule (g&~3)|((g&3)^((g>>3)&3))
  auto stageV = [&](int bi, int kt) {
    int g = wid * 64 + lane;
    int src = (g & ~3) | ((g & 3) ^ ((lane >> 3) & 3));
    gload_lds16(vbase + (size_t)kt * 4096 + src * 16, &Vs[bi][wid * 1024]);
  };

  bf16x8 qf[4];
  const bf16* qrow = q + (size_t)(b * 2048 + qb + lq) * 1024 + h * 64 + hi * 8;
#pragma unroll
  for (int i = 0; i < 4; ++i) qf[i] = *(const bf16x8*)(qrow + i * 16);

  f32x16 O0 = {}, O1 = {};
  float m = -__builtin_inff(), l = 0.f;

  stageK(0, 0);
  stageV(0, 0);
  __syncthreads();
  int cur = 0;

  for (int t = 0; t < nt; ++t) {
    if (t + 1 < nt) {
      stageK(cur ^ 1, t + 1);
      stageV(cur ^ 1, t + 1);
    }

    // K frag i: logical granule lq*8+i*2+hi, swizzled ^(lq&7)
    bf16x8 kf[4];
#pragma unroll
    for (int i = 0; i < 4; ++i)
      kf[i] = *(const bf16x8*)&Ks[cur][((lq * 8 + i * 2 + hi) ^ (lq & 7)) * 16];
    // V frag (d,ks): logical granule (d*32+lq)*4 + ks*2+hi, col bits ^((lq>>1)&3)
    bf16x8 vf[2][2];
#pragma unroll
    for (int d = 0; d < 2; ++d)
#pragma unroll
      for (int ks = 0; ks < 2; ++ks)
        vf[d][ks] = *(const bf16x8*)
            &Vs[cur][((d * 32 + lq) * 4 + ((ks * 2 + hi) ^ ((lq >> 1) & 3))) * 16];

    // S^T[key][q]: 4 MFMAs over dk=64
    f32x16 S = {};
#pragma unroll
    for (int i = 0; i < 4; ++i)
      S = __builtin_amdgcn_mfma_f32_32x32x16_bf16(kf[i], qf[i], S, 0, 0, 0);

    if (t == nt - 1) {  // diagonal tile: mask key_local > q_local
#pragma unroll
      for (int r = 0; r < 16; ++r) {
        int kr = (r & 3) + 8 * (r >> 2) + 4 * hi;
        if (kr > lq) S[r] = -__builtin_inff();
      }
    }

    // row max
    float pm = fmaxf(fmaxf(S[0], S[1]), S[2]);
    pm = fmaxf(fmaxf(pm, S[3]), S[4]);
    pm = fmaxf(fmaxf(pm, S[5]), S[6]);
    pm = fmaxf(fmaxf(pm, S[7]), S[8]);
    pm = fmaxf(fmaxf(pm, S[9]), S[10]);
    pm = fmaxf(fmaxf(pm, S[11]), S[12]);
    pm = fmaxf(fmaxf(pm, S[13]), S[14]);
    pm = fmaxf(pm, S[15]);
    pm = fmaxf(pm, __shfl_xor(pm, 32));

    if (!__all(pm <= m + 8.0f)) {  // rescale path (rare after warmup)
      float mn = fmaxf(m, pm);
      float fac = __builtin_amdgcn_exp2f(m - mn);
      m = mn;
      l *= fac;
      if (hi == 0) bc[wid][lq] = fac;
      __threadfence_block();
#pragma unroll
      for (int r = 0; r < 16; ++r) {
        float fr = bc[wid][(r & 3) + 8 * (r >> 2) + 4 * hi];
        O0[r] *= fr;
        O1[r] *= fr;
      }
    }

    // exp + pack rolling pairs
    float ls = 0.f;
    u32 w[8];
#pragma unroll
    for (int i = 0; i < 8; ++i) {
      float e0 = __builtin_amdgcn_exp2f(S[2 * i] - m);
      float e1 = __builtin_amdgcn_exp2f(S[2 * i + 1] - m);
      ls += e0 + e1;
      w[i] = pack2(e0, e1);
    }
    ls += __shfl_xor(ls, 32);
    l += ls;

    // rebuild PV A-fragments (verified round-2 path): shfl_xor(32) + select
    u32 sw0 = (u32)__shfl_xor((int)w[0], 32), sw1 = (u32)__shfl_xor((int)w[1], 32);
    u32 sw2 = (u32)__shfl_xor((int)w[2], 32), sw3 = (u32)__shfl_xor((int)w[3], 32);
    u32 sw4 = (u32)__shfl_xor((int)w[4], 32), sw5 = (u32)__shfl_xor((int)w[5], 32);
    u32 sw6 = (u32)__shfl_xor((int)w[6], 32), sw7 = (u32)__shfl_xor((int)w[7], 32);
    union { u32 d[4]; bf16x8 v; } f0, f1;
    f0.d[0] = hi ? sw2 : w[0];
    f0.d[1] = hi ? sw3 : w[1];
    f0.d[2] = hi ? w[2] : sw0;
    f0.d[3] = hi ? w[3] : sw1;
    f1.d[0] = hi ? sw6 : w[4];
    f1.d[1] = hi ? sw7 : w[5];
    f1.d[2] = hi ? w[6] : sw4;
    f1.d[3] = hi ? w[7] : sw5;

    O0 = __builtin_amdgcn_mfma_f32_32x32x16_bf16(f0.v, vf[0][0], O0, 0, 0, 0);
    O0 = __builtin_amdgcn_mfma_f32_32x32x16_bf16(f1.v, vf[0][1], O0, 0, 0, 0);
    O1 = __builtin_amdgcn_mfma_f32_32x32x16_bf16(f0.v, vf[1][0], O1, 0, 0, 0);
    O1 = __builtin_amdgcn_mfma_f32_32x32x16_bf16(f1.v, vf[1][1], O1, 0, 0, 0);

    __syncthreads();  // staging drained + all waves done reading
    cur ^= 1;
  }

  // epilogue: normalize by 1/l (broadcast per output row) and store
  float linv = 1.0f / l;
  if (hi == 0) bc[wid][lq] = linv;
  __threadfence_block();
#pragma unroll
  for (int r = 0; r < 16; ++r) {
    int row = (r & 3) + 8 * (r >> 2) + 4 * hi;
    float sc = bc[wid][row];
    size_t base = (size_t)(b * 2048 + qb + row) * 1024 + h * 64;
    o[base + lq] = (bf16)(O0[r] * sc);
    o[base + 32 + lq] = (bf16)(O1[r] * sc);
  }
}

// ---------------- launch ----------------
extern "C" void kernel_launch(void* const* d_in, const int* in_sizes, int n_in,
                              void* d_out, int out_size, void* d_ws, size_t ws_size,
                              hipStream_t stream) {
  const float* Q  = (const float*)d_in[0];
  const float* K  = (const float*)d_in[1];
  const float* V  = (const float*)d_in[2];
  const float* wq = (const float*)d_in[3];
  const float* wk = (const float*)d_in[4];
  const float* wv = (const float*)d_in[5];
  const float* wo = (const float*)d_in[6];
  float* out = (float*)d_out;

  char* ws = (char*)d_ws;
  bf16* Qb   = (bf16*)(ws);                          // 8192x1024  (16 MB)
  bf16* Kb   = (bf16*)(ws + (16ull << 20));          // 16 MB  (Kb;Vb contiguous = KVb)
  bf16* Vb   = (bf16*)(ws + (32ull << 20));          // 16 MB
  bf16* qp   = (bf16*)(ws + (48ull << 20));          // q proj bf16, 16 MB
  bf16* ab   = (bf16*)(ws + (64ull << 20));          // attn out bf16, 16 MB
  bf16* kp   = (bf16*)(ws + (80ull << 20));          // [b][key][64], 1 MB
  bf16* vTp  = (bf16*)(ws + (81ull << 20));          // [b][tile][d][key32], 1 MB
  bf16* wqT  = (bf16*)(ws + (82ull << 20));          // 2 MB
  bf16* woT  = (bf16*)(ws + (84ull << 20));          // 2 MB
  bf16* wkvT = (bf16*)(ws + (86ull << 20));          // [128][1024] = 256 KB

  const int N8 = 8192 * 1024 / 8;
  cast3_kernel<<<dim3(1024, 3), 256, 0, stream>>>(Q, K, V, Qb, Kb, Vb, N8);

  // fold softmax scale (1/sqrt(64)) and log2(e) into Wq (exp2-based softmax)
  const float SCALE = 0.125f * 1.44269504088896340736f;
  transpose_all<<<dim3(68, 32), 256, 0, stream>>>(wq, wk, wv, wo, wqT, wkvT, woT, SCALE);

  proj_kernel<<<640, 256, 0, stream>>>(Qb, Kb, wqT, wkvT, qp, kp, vTp);

  attn_kernel<<<dim3(64, 4, 4), 256, 0, stream>>>(qp, kp, vTp, ab);

  gemm_bt<float><<<dim3(64, 8), 256, 0, stream>>>(ab, woT, out, 8192, 1024, 1024);
}

// Round 8
// 165.743 us; speedup vs baseline: 1.9315x; 1.1778x over previous
//
#include <hip/hip_runtime.h>

typedef __bf16 bf16;
typedef unsigned int u32;
typedef __bf16 bf16x8 __attribute__((ext_vector_type(8)));
typedef float f32x4 __attribute__((ext_vector_type(4)));
typedef float f32x16 __attribute__((ext_vector_type(16)));

#define DEV __device__ __forceinline__

// async global->LDS, 16B per lane; lds base must be wave-uniform (HW adds lane*16);
// global source address IS per-lane (m173)
DEV void gload_lds16(const void* g, void* l) {
  __builtin_amdgcn_global_load_lds((const __attribute__((address_space(1))) void*)g,
                                   (__attribute__((address_space(3))) void*)l,
                                   16, 0, 0);
}

DEV u32 pack2(float a, float b) {
  unsigned short ua = __builtin_bit_cast(unsigned short, (bf16)a);
  unsigned short ub = __builtin_bit_cast(unsigned short, (bf16)b);
  return (u32)ua | ((u32)ub << 16);
}

// ---------------- cast fp32 -> bf16 for Q,K,V in one launch ----------------
__global__ void cast3_kernel(const float* __restrict__ a, const float* __restrict__ b,
                             const float* __restrict__ c, bf16* __restrict__ oa,
                             bf16* __restrict__ ob, bf16* __restrict__ oc, int n8) {
  const float* in = blockIdx.y == 0 ? a : blockIdx.y == 1 ? b : c;
  bf16* out = blockIdx.y == 0 ? oa : blockIdx.y == 1 ? ob : oc;
  int idx = blockIdx.x * blockDim.x + threadIdx.x;
  int stride = gridDim.x * blockDim.x;
  for (int i = idx; i < n8; i += stride) {
    const float4* p = (const float4*)(in + (size_t)i * 8);
    float4 x = p[0], y = p[1];
    bf16x8 v;
    v[0] = (bf16)x.x; v[1] = (bf16)x.y; v[2] = (bf16)x.z; v[3] = (bf16)x.w;
    v[4] = (bf16)y.x; v[5] = (bf16)y.y; v[6] = (bf16)y.z; v[7] = (bf16)y.w;
    *(bf16x8*)(out + (size_t)i * 8) = v;
  }
}

// ---------------- all weight transposes in ONE launch ----------------
__global__ void transpose_all(const float* __restrict__ wq, const float* __restrict__ wk,
                              const float* __restrict__ wv, const float* __restrict__ wo,
                              bf16* __restrict__ wqT, bf16* __restrict__ wkvT,
                              bf16* __restrict__ woT, float scale_q) {
  __shared__ float tile[32][33];
  int x = blockIdx.x;
  const float* in;
  bf16* out;
  int C;
  float scale = 1.0f;
  int c0;
  if (x < 32)      { in = wq; out = wqT;             C = 1024; c0 = x * 32; scale = scale_q; }
  else if (x < 34) { in = wk; out = wkvT;            C = 64;   c0 = (x - 32) * 32; }
  else if (x < 36) { in = wv; out = wkvT + 64 * 1024; C = 64;  c0 = (x - 34) * 32; }
  else             { in = wo; out = woT;             C = 1024; c0 = (x - 36) * 32; }
  int r0 = blockIdx.y * 32;
  int tx = threadIdx.x & 31, ty = threadIdx.x >> 5;  // 256 threads = 32x8
  for (int i = ty; i < 32; i += 8) tile[i][tx] = in[(size_t)(r0 + i) * C + c0 + tx];
  __syncthreads();
  for (int i = ty; i < 32; i += 8)
    out[(size_t)(c0 + i) * 1024 + r0 + tx] = (bf16)(tile[tx][i] * scale);
}

// ---------------- bf16 GEMM, B transposed (Bt[N][K]), m97 structure ----------------
template <typename OutT>
__global__ __launch_bounds__(256)
void gemm_bt(const bf16* __restrict__ A, const bf16* __restrict__ Bt,
             OutT* __restrict__ C, int M, int N, int K) {
  __shared__ __align__(16) bf16 As[128 * 32];
  __shared__ __align__(16) bf16 Bs[128 * 32];
  const int tid = threadIdx.x;
  const int wid = tid >> 6, lane = tid & 63;
  const int wr = wid >> 1, wc = wid & 1;
  const int lx = lane & 15, g = lane >> 4;
  const size_t bm = (size_t)blockIdx.x * 128;
  const size_t bn = (size_t)blockIdx.y * 128;
  f32x4 acc[4][4] = {};

  for (int k0 = 0; k0 < K; k0 += 32) {
#pragma unroll
    for (int i = 0; i < 2; ++i) {
      int c = i * 256 + wid * 64 + lane;
      const bf16* gp = A + (bm + (size_t)(c >> 2)) * K + k0 + (c & 3) * 8;
      gload_lds16(gp, (char*)As + (size_t)(i * 256 + wid * 64) * 16);
    }
#pragma unroll
    for (int i = 0; i < 2; ++i) {
      int c = i * 256 + wid * 64 + lane;
      const bf16* gp = Bt + (bn + (size_t)(c >> 2)) * K + k0 + (c & 3) * 8;
      gload_lds16(gp, (char*)Bs + (size_t)(i * 256 + wid * 64) * 16);
    }
    __syncthreads();
    bf16x8 af[4], bfr[4];
#pragma unroll
    for (int m = 0; m < 4; ++m)
      af[m] = *(const bf16x8*)&As[(wr * 64 + m * 16 + lx) * 32 + g * 8];
#pragma unroll
    for (int n = 0; n < 4; ++n)
      bfr[n] = *(const bf16x8*)&Bs[(wc * 64 + n * 16 + lx) * 32 + g * 8];
#pragma unroll
    for (int m = 0; m < 4; ++m)
#pragma unroll
      for (int n = 0; n < 4; ++n)
        acc[m][n] = __builtin_amdgcn_mfma_f32_16x16x32_bf16(af[m], bfr[n], acc[m][n], 0, 0, 0);
    __syncthreads();
  }

#pragma unroll
  for (int m = 0; m < 4; ++m)
#pragma unroll
    for (int n = 0; n < 4; ++n) {
      size_t row = bm + wr * 64 + m * 16 + g * 4;
      size_t col = bn + wc * 64 + n * 16 + lx;
#pragma unroll
      for (int j = 0; j < 4; ++j)
        C[(row + j) * N + col] = (OutT)acc[m][n][j];
    }
}

// ---------------- fused projections: q = Qb@wqT ; [k|v] = [Kb;Vb]@[wk|wv] ----------
__global__ __launch_bounds__(256)
void proj_kernel(const bf16* __restrict__ Qb, const bf16* __restrict__ KVb,
                 const bf16* __restrict__ wqT, const bf16* __restrict__ wkvT,
                 bf16* __restrict__ qp, bf16* __restrict__ kp, bf16* __restrict__ vTp) {
  const int bid = blockIdx.x;
  const bool isq = bid < 512;
  const bf16* A = isq ? Qb : KVb;
  const bf16* Bt = isq ? wqT : wkvT;
  const size_t bm = isq ? (size_t)(bid & 63) * 128 : (size_t)(bid - 512) * 128;
  const size_t bn = isq ? (size_t)(bid >> 6) * 128 : 0;

  __shared__ __align__(16) bf16 As[128 * 32];
  __shared__ __align__(16) bf16 Bs[128 * 32];
  const int tid = threadIdx.x;
  const int wid = tid >> 6, lane = tid & 63;
  const int wr = wid >> 1, wc = wid & 1;
  const int lx = lane & 15, g = lane >> 4;
  f32x4 acc[4][4] = {};

  for (int k0 = 0; k0 < 1024; k0 += 32) {
#pragma unroll
    for (int i = 0; i < 2; ++i) {
      int c = i * 256 + wid * 64 + lane;
      const bf16* gp = A + (bm + (size_t)(c >> 2)) * 1024 + k0 + (c & 3) * 8;
      gload_lds16(gp, (char*)As + (size_t)(i * 256 + wid * 64) * 16);
    }
#pragma unroll
    for (int i = 0; i < 2; ++i) {
      int c = i * 256 + wid * 64 + lane;
      const bf16* gp = Bt + (bn + (size_t)(c >> 2)) * 1024 + k0 + (c & 3) * 8;
      gload_lds16(gp, (char*)Bs + (size_t)(i * 256 + wid * 64) * 16);
    }
    __syncthreads();
    bf16x8 af[4], bfr[4];
#pragma unroll
    for (int m = 0; m < 4; ++m)
      af[m] = *(const bf16x8*)&As[(wr * 64 + m * 16 + lx) * 32 + g * 8];
#pragma unroll
    for (int n = 0; n < 4; ++n)
      bfr[n] = *(const bf16x8*)&Bs[(wc * 64 + n * 16 + lx) * 32 + g * 8];
#pragma unroll
    for (int m = 0; m < 4; ++m)
#pragma unroll
      for (int n = 0; n < 4; ++n)
        acc[m][n] = __builtin_amdgcn_mfma_f32_16x16x32_bf16(af[m], bfr[n], acc[m][n], 0, 0, 0);
    __syncthreads();
  }

#pragma unroll
  for (int m = 0; m < 4; ++m)
#pragma unroll
    for (int n = 0; n < 4; ++n) {
      size_t row = bm + wr * 64 + m * 16 + g * 4;
      size_t col = bn + wc * 64 + n * 16 + lx;
#pragma unroll
      for (int j = 0; j < 4; ++j) {
        float v = acc[m][n][j];
        size_t r = row + j;
        if (isq) {
          qp[r * 1024 + col] = (bf16)v;
        } else if (col < 64) {
          if (r < 8192) kp[r * 64 + col] = (bf16)v;  // [b*2048+key][64]
        } else {
          if (r >= 8192) {
            size_t rr = r - 8192;
            size_t bb = rr >> 11, nn = rr & 2047;
            vTp[bb * 131072 + (nn >> 5) * 2048 + (col - 64) * 32 + (nn & 31)] = (bf16)v;
          }
        }
      }
    }
}

// ---------------- causal multi-query flash attention ----------------
// grid (32 strip-pairs, 4 head-groups, 4 batch) = 512 blocks, 4 waves = 4 HEADS
// sharing one (strip,batch) [round-6 uniform pairing: rep 0 = strip 63-p (long),
// rep 1 = strip p]. K/V staged once/block to LDS (dbuf, XOR-swizzled both sides).
// KVBLK=64: two 32-key subtiles per barrier round (2x in-wave ILP, half the
// barriers); odd tile handled by a 32-key diagonal tail. setprio(1) around MFMA
// clusters (T5). Softmax in-register (verified round-2 path).
__global__ __launch_bounds__(256, 2)
void attn_kernel(const bf16* __restrict__ q, const bf16* __restrict__ k,
                 const bf16* __restrict__ vt, bf16* __restrict__ o) {
  const int hg = blockIdx.y, b = blockIdx.z;
  const int wid = threadIdx.x >> 6, lane = threadIdx.x & 63;
  const int lq = lane & 31, hi = lane >> 5;
  const int h = hg * 4 + wid;
  const int pairIdx = blockIdx.x;  // 0..31

  __shared__ __align__(16) char Ks[2][8192];  // 2 x 4KB subtiles (32 keys x 64d each)
  __shared__ __align__(16) char Vs[2][8192];  // 2 x 4KB subtiles (64d x 32 keys each)
  __shared__ float bc[4][32];

  const bf16* kb = k + (size_t)b * 2048 * 64;                // [key][64]
  const char* vbase = (const char*)vt + (size_t)b * 262144;  // [tile][d][key32]

  // stage one 4KB K tile kt into buffer bi, subtile sub (swizzle at SOURCE, rule 21)
  auto stageK = [&](int bi, int kt, int sub) {
    int src = (wid * 64 + lane) ^ ((lane >> 3) & 7);
    gload_lds16((const char*)(kb + (size_t)kt * 2048) + src * 16,
                &Ks[bi][sub * 4096 + wid * 1024]);
  };
  auto stageV = [&](int bi, int kt, int sub) {
    int g = wid * 64 + lane;
    int src = (g & ~3) | ((g & 3) ^ ((lane >> 3) & 3));
    gload_lds16(vbase + (size_t)kt * 4096 + src * 16, &Vs[bi][sub * 4096 + wid * 1024]);
  };

  bf16x8 qf[4];

  // QK^T for one 32-key subtile: S^T[key][q], lane holds 16 scores of query lq,
  // key = base + (r&3)+8*(r>>2)+4*hi
  auto qkt = [&](int cur, int sub) -> f32x16 {
    bf16x8 kf[4];
#pragma unroll
    for (int i = 0; i < 4; ++i)
      kf[i] = *(const bf16x8*)&Ks[cur][sub * 4096 + ((lq * 8 + i * 2 + hi) ^ (lq & 7)) * 16];
    f32x16 S = {};
#pragma unroll
    for (int i = 0; i < 4; ++i)
      S = __builtin_amdgcn_mfma_f32_32x32x16_bf16(kf[i], qf[i], S, 0, 0, 0);
    return S;
  };
  auto loadV = [&](int cur, int sub, bf16x8 (&vf)[2][2]) {
#pragma unroll
    for (int d = 0; d < 2; ++d)
#pragma unroll
      for (int ks = 0; ks < 2; ++ks)
        vf[d][ks] = *(const bf16x8*)&Vs[cur][sub * 4096 +
                        ((d * 32 + lq) * 4 + ((ks * 2 + hi) ^ ((lq >> 1) & 3))) * 16];
  };
  // rebuild PV A-fragments from 8 packed words (verified round-2 path)
  auto rebuild = [&](const u32 w[8], bf16x8& o0, bf16x8& o1) {
    u32 sw0 = (u32)__shfl_xor((int)w[0], 32), sw1 = (u32)__shfl_xor((int)w[1], 32);
    u32 sw2 = (u32)__shfl_xor((int)w[2], 32), sw3 = (u32)__shfl_xor((int)w[3], 32);
    u32 sw4 = (u32)__shfl_xor((int)w[4], 32), sw5 = (u32)__shfl_xor((int)w[5], 32);
    u32 sw6 = (u32)__shfl_xor((int)w[6], 32), sw7 = (u32)__shfl_xor((int)w[7], 32);
    union { u32 d[4]; bf16x8 v; } f0, f1;
    f0.d[0] = hi ? sw2 : w[0];
    f0.d[1] = hi ? sw3 : w[1];
    f0.d[2] = hi ? w[2] : sw0;
    f0.d[3] = hi ? w[3] : sw1;
    f1.d[0] = hi ? sw6 : w[4];
    f1.d[1] = hi ? sw7 : w[5];
    f1.d[2] = hi ? w[6] : sw4;
    f1.d[3] = hi ? w[7] : sw5;
    o0 = f0.v;
    o1 = f1.v;
  };

#pragma unroll 1
  for (int rep = 0; rep < 2; ++rep) {
    const int strip = rep ? pairIdx : 63 - pairIdx;
    const int qb = strip * 32;
    const int nt = strip + 1;
    const int nfull = nt >> 1, tail = nt & 1;

    const bf16* qrow = q + (size_t)(b * 2048 + qb + lq) * 1024 + h * 64 + hi * 8;
#pragma unroll
    for (int i = 0; i < 4; ++i) qf[i] = *(const bf16x8*)(qrow + i * 16);

    f32x16 O0 = {}, O1 = {};
    float m = -__builtin_inff(), l = 0.f;

    __syncthreads();  // previous rep's readers done before restaging buffers
    if (nfull) {
      stageK(0, 0, 0); stageK(0, 1, 1);
      stageV(0, 0, 0); stageV(0, 1, 1);
    } else {
      stageK(0, 0, 0); stageV(0, 0, 0);
    }
    __syncthreads();
    int cur = 0;

    for (int r2 = 0; r2 < nfull; ++r2) {
      if (r2 + 1 < nfull) {
        stageK(cur ^ 1, 2 * r2 + 2, 0); stageK(cur ^ 1, 2 * r2 + 3, 1);
        stageV(cur ^ 1, 2 * r2 + 2, 0); stageV(cur ^ 1, 2 * r2 + 3, 1);
      } else if (tail) {
        stageK(cur ^ 1, 2 * nfull, 0); stageV(cur ^ 1, 2 * nfull, 0);
      }

      __builtin_amdgcn_s_setprio(1);
      f32x16 SA = qkt(cur, 0);
      f32x16 SB = qkt(cur, 1);
      __builtin_amdgcn_s_setprio(0);

      if (r2 == nfull - 1 && !tail) {  // subtile B is the diagonal tile
#pragma unroll
        for (int r = 0; r < 16; ++r) {
          int kr = (r & 3) + 8 * (r >> 2) + 4 * hi;
          if (kr > lq) SB[r] = -__builtin_inff();
        }
      }

      // joint row max over 32 scores
      float pm = fmaxf(fmaxf(SA[0], SA[1]), SA[2]);
      pm = fmaxf(fmaxf(pm, SA[3]), SA[4]);
      pm = fmaxf(fmaxf(pm, SA[5]), SA[6]);
      pm = fmaxf(fmaxf(pm, SA[7]), SA[8]);
      pm = fmaxf(fmaxf(pm, SA[9]), SA[10]);
      pm = fmaxf(fmaxf(pm, SA[11]), SA[12]);
      pm = fmaxf(fmaxf(pm, SA[13]), SA[14]);
      pm = fmaxf(fmaxf(pm, SA[15]), SB[0]);
      pm = fmaxf(fmaxf(pm, SB[1]), SB[2]);
      pm = fmaxf(fmaxf(pm, SB[3]), SB[4]);
      pm = fmaxf(fmaxf(pm, SB[5]), SB[6]);
      pm = fmaxf(fmaxf(pm, SB[7]), SB[8]);
      pm = fmaxf(fmaxf(pm, SB[9]), SB[10]);
      pm = fmaxf(fmaxf(pm, SB[11]), SB[12]);
      pm = fmaxf(fmaxf(pm, SB[13]), SB[14]);
      pm = fmaxf(pm, SB[15]);
      pm = fmaxf(pm, __shfl_xor(pm, 32));

      if (!__all(pm <= m + 8.0f)) {  // rescale path (rare after warmup)
        float mn = fmaxf(m, pm);
        float fac = __builtin_amdgcn_exp2f(m - mn);
        m = mn;
        l *= fac;
        if (hi == 0) bc[wid][lq] = fac;
        __threadfence_block();
#pragma unroll
        for (int r = 0; r < 16; ++r) {
          float fr = bc[wid][(r & 3) + 8 * (r >> 2) + 4 * hi];
          O0[r] *= fr;
          O1[r] *= fr;
        }
      }

      float lsA = 0.f, lsB = 0.f;
      u32 wA[8], wB[8];
#pragma unroll
      for (int i = 0; i < 8; ++i) {
        float e0 = __builtin_amdgcn_exp2f(SA[2 * i] - m);
        float e1 = __builtin_amdgcn_exp2f(SA[2 * i + 1] - m);
        lsA += e0 + e1;
        wA[i] = pack2(e0, e1);
      }
#pragma unroll
      for (int i = 0; i < 8; ++i) {
        float e0 = __builtin_amdgcn_exp2f(SB[2 * i] - m);
        float e1 = __builtin_amdgcn_exp2f(SB[2 * i + 1] - m);
        lsB += e0 + e1;
        wB[i] = pack2(e0, e1);
      }
      float ls = lsA + lsB;
      ls += __shfl_xor(ls, 32);
      l += ls;

      bf16x8 f0A, f1A, f0B, f1B;
      rebuild(wA, f0A, f1A);
      rebuild(wB, f0B, f1B);

      bf16x8 vfA[2][2], vfB[2][2];
      loadV(cur, 0, vfA);
      loadV(cur, 1, vfB);

      __builtin_amdgcn_s_setprio(1);
      O0 = __builtin_amdgcn_mfma_f32_32x32x16_bf16(f0A, vfA[0][0], O0, 0, 0, 0);
      O0 = __builtin_amdgcn_mfma_f32_32x32x16_bf16(f1A, vfA[0][1], O0, 0, 0, 0);
      O0 = __builtin_amdgcn_mfma_f32_32x32x16_bf16(f0B, vfB[0][0], O0, 0, 0, 0);
      O0 = __builtin_amdgcn_mfma_f32_32x32x16_bf16(f1B, vfB[0][1], O0, 0, 0, 0);
      O1 = __builtin_amdgcn_mfma_f32_32x32x16_bf16(f0A, vfA[1][0], O1, 0, 0, 0);
      O1 = __builtin_amdgcn_mfma_f32_32x32x16_bf16(f1A, vfA[1][1], O1, 0, 0, 0);
      O1 = __builtin_amdgcn_mfma_f32_32x32x16_bf16(f0B, vfB[1][0], O1, 0, 0, 0);
      O1 = __builtin_amdgcn_mfma_f32_32x32x16_bf16(f1B, vfB[1][1], O1, 0, 0, 0);
      __builtin_amdgcn_s_setprio(0);

      __syncthreads();  // own staging drained + all waves done reading
      cur ^= 1;
    }

    if (tail) {  // final 32-key diagonal tile (nt odd), staged in buffer `cur` sub 0
      __builtin_amdgcn_s_setprio(1);
      f32x16 S = qkt(cur, 0);
      __builtin_amdgcn_s_setprio(0);
#pragma unroll
      for (int r = 0; r < 16; ++r) {
        int kr = (r & 3) + 8 * (r >> 2) + 4 * hi;
        if (kr > lq) S[r] = -__builtin_inff();
      }
      float pm = fmaxf(fmaxf(S[0], S[1]), S[2]);
      pm = fmaxf(fmaxf(pm, S[3]), S[4]);
      pm = fmaxf(fmaxf(pm, S[5]), S[6]);
      pm = fmaxf(fmaxf(pm, S[7]), S[8]);
      pm = fmaxf(fmaxf(pm, S[9]), S[10]);
      pm = fmaxf(fmaxf(pm, S[11]), S[12]);
      pm = fmaxf(fmaxf(pm, S[13]), S[14]);
      pm = fmaxf(pm, S[15]);
      pm = fmaxf(pm, __shfl_xor(pm, 32));

      if (!__all(pm <= m + 8.0f)) {
        float mn = fmaxf(m, pm);
        float fac = __builtin_amdgcn_exp2f(m - mn);
        m = mn;
        l *= fac;
        if (hi == 0) bc[wid][lq] = fac;
        __threadfence_block();
#pragma unroll
        for (int r = 0; r < 16; ++r) {
          float fr = bc[wid][(r & 3) + 8 * (r >> 2) + 4 * hi];
          O0[r] *= fr;
          O1[r] *= fr;
        }
      }

      float ls = 0.f;
      u32 w[8];
#pragma unroll
      for (int i = 0; i < 8; ++i) {
        float e0 = __builtin_amdgcn_exp2f(S[2 * i] - m);
        float e1 = __builtin_amdgcn_exp2f(S[2 * i + 1] - m);
        ls += e0 + e1;
        w[i] = pack2(e0, e1);
      }
      ls += __shfl_xor(ls, 32);
      l += ls;

      bf16x8 f0, f1;
      rebuild(w, f0, f1);
      bf16x8 vf[2][2];
      loadV(cur, 0, vf);

      __builtin_amdgcn_s_setprio(1);
      O0 = __builtin_amdgcn_mfma_f32_32x32x16_bf16(f0, vf[0][0], O0, 0, 0, 0);
      O0 = __builtin_amdgcn_mfma_f32_32x32x16_bf16(f1, vf[0][1], O0, 0, 0, 0);
      O1 = __builtin_amdgcn_mfma_f32_32x32x16_bf16(f0, vf[1][0], O1, 0, 0, 0);
      O1 = __builtin_amdgcn_mfma_f32_32x32x16_bf16(f1, vf[1][1], O1, 0, 0, 0);
      __builtin_amdgcn_s_setprio(0);
    }

    // epilogue: normalize by 1/l (broadcast per output row) and store
    float linv = 1.0f / l;
    if (hi == 0) bc[wid][lq] = linv;
    __threadfence_block();
#pragma unroll
    for (int r = 0; r < 16; ++r) {
      int row = (r & 3) + 8 * (r >> 2) + 4 * hi;
      float sc = bc[wid][row];
      size_t base = (size_t)(b * 2048 + qb + row) * 1024 + h * 64;
      o[base + lq] = (bf16)(O0[r] * sc);
      o[base + 32 + lq] = (bf16)(O1[r] * sc);
    }
  }
}

// ---------------- launch ----------------
extern "C" void kernel_launch(void* const* d_in, const int* in_sizes, int n_in,
                              void* d_out, int out_size, void* d_ws, size_t ws_size,
                              hipStream_t stream) {
  const float* Q  = (const float*)d_in[0];
  const float* K  = (const float*)d_in[1];
  const float* V  = (const float*)d_in[2];
  const float* wq = (const float*)d_in[3];
  const float* wk = (const float*)d_in[4];
  const float* wv = (const float*)d_in[5];
  const float* wo = (const float*)d_in[6];
  float* out = (float*)d_out;

  char* ws = (char*)d_ws;
  bf16* Qb   = (bf16*)(ws);                          // 8192x1024  (16 MB)
  bf16* Kb   = (bf16*)(ws + (16ull << 20));          // 16 MB  (Kb;Vb contiguous = KVb)
  bf16* Vb   = (bf16*)(ws + (32ull << 20));          // 16 MB
  bf16* qp   = (bf16*)(ws + (48ull << 20));          // q proj bf16, 16 MB
  bf16* ab   = (bf16*)(ws + (64ull << 20));          // attn out bf16, 16 MB
  bf16* kp   = (bf16*)(ws + (80ull << 20));          // [b][key][64], 1 MB
  bf16* vTp  = (bf16*)(ws + (81ull << 20));          // [b][tile][d][key32], 1 MB
  bf16* wqT  = (bf16*)(ws + (82ull << 20));          // 2 MB
  bf16* woT  = (bf16*)(ws + (84ull << 20));          // 2 MB
  bf16* wkvT = (bf16*)(ws + (86ull << 20));          // [128][1024] = 256 KB

  const int N8 = 8192 * 1024 / 8;
  cast3_kernel<<<dim3(1024, 3), 256, 0, stream>>>(Q, K, V, Qb, Kb, Vb, N8);

  // fold softmax scale (1/sqrt(64)) and log2(e) into Wq (exp2-based softmax)
  const float SCALE = 0.125f * 1.44269504088896340736f;
  transpose_all<<<dim3(68, 32), 256, 0, stream>>>(wq, wk, wv, wo, wqT, wkvT, woT, SCALE);

  proj_kernel<<<640, 256, 0, stream>>>(Qb, Kb, wqT, wkvT, qp, kp, vTp);

  attn_kernel<<<dim3(32, 4, 4), 256, 0, stream>>>(qp, kp, vTp, ab);

  gemm_bt<float><<<dim3(64, 8), 256, 0, stream>>>(ab, woT, out, 8192, 1024, 1024);
}